// Round 11
// baseline (214.755 us; speedup 1.0000x reference)
//
#include <hip/hip_runtime.h>
#include <hip/hip_fp16.h>
#include <cstddef>
#include <cstdint>

namespace {

constexpr int N  = 50000;   // nodes  (must fit u16 for edge packing)
constexpr int E  = 800000;  // edges
constexpr int DH = 64;      // hidden dim
constexpr int DO = 32;      // output dim
constexpr int NB = (N + 255) / 256;   // 196 scan blocks
static_assert(N < 65536, "src packed as u16");
static_assert(NB <= 256, "phase-B single tile");
static_assert((E & 3) == 0, "4-edges-per-thread, no tail");

__device__ inline float bf2f(uint16_t u) {
    union { uint32_t u; float f; } c; c.u = (uint32_t)u << 16; return c.f;
}
__device__ inline uint16_t f2bf(float f) {   // RTNE
    union { float f; uint32_t u; } c; c.f = f;
    uint32_t r = c.u + 0x7FFFu + ((c.u >> 16) & 1u);
    return (uint16_t)(r >> 16);
}
// unpack packed pair of bf16 (low = first in memory)
__device__ inline void bf2x(uint32_t p, float& a, float& b) {
    union { uint32_t u; float f; } c0, c1;
    c0.u = p << 16; c1.u = p & 0xFFFF0000u;
    a = c0.f; b = c1.f;
}

// ---------------------------------------------------------------------------
__global__ void k_zero(int* __restrict__ cnt) {
    int i = blockIdx.x * blockDim.x + threadIdx.x;
    if (i < N) cnt[i] = 0;
}

// in-degree histogram: 4 edges/thread -> 4 independent atomic chains
__global__ void k_count(const int* __restrict__ dst, int* __restrict__ cnt) {
    int t = blockIdx.x * blockDim.x + threadIdx.x;
    if (t >= E / 4) return;
    const int4 d4 = reinterpret_cast<const int4*>(dst)[t];
    atomicAdd(&cnt[d4.x], 1);
    atomicAdd(&cnt[d4.y], 1);
    atomicAdd(&cnt[d4.z], 1);
    atomicAdd(&cnt[d4.w], 1);
}

// ---------------------------------------------------------------------------
// Device-wide exclusive scan of cnt, 3 phases.
__global__ void k_scanA(const int* __restrict__ cnt, int* __restrict__ incl,
                        int* __restrict__ bsum) {
    __shared__ int ts[256];
    const int t = threadIdx.x;
    const int i = blockIdx.x * 256 + t;
    const int v = (i < N) ? cnt[i] : 0;
    ts[t] = v;
    __syncthreads();
#pragma unroll
    for (int off = 1; off < 256; off <<= 1) {
        const int u = (t >= off) ? ts[t - off] : 0;
        __syncthreads();
        ts[t] += u;
        __syncthreads();
    }
    if (i < N) incl[i] = ts[t];
    if (t == 255) bsum[blockIdx.x] = ts[255];
}

__global__ void k_scanB(int* __restrict__ bsum) {
    __shared__ int ts[256];
    const int t = threadIdx.x;
    const int v = (t < NB) ? bsum[t] : 0;
    ts[t] = v;
    __syncthreads();
#pragma unroll
    for (int off = 1; off < 256; off <<= 1) {
        const int u = (t >= off) ? ts[t - off] : 0;
        __syncthreads();
        ts[t] += u;
        __syncthreads();
    }
    if (t < NB) bsum[t] = ts[t] - v;    // exclusive base for block t
}

__global__ void k_scanC(const int* __restrict__ cnt, const int* __restrict__ incl,
                        const int* __restrict__ bbase, int* __restrict__ rowptr,
                        int* __restrict__ cursor, float* __restrict__ dinv) {
    const int i = blockIdx.x * 256 + threadIdx.x;
    if (i >= N) return;
    const int c    = cnt[i];
    const int excl = bbase[blockIdx.x] + incl[i] - c;
    rowptr[i] = excl;
    cursor[i] = excl;
    dinv[i]   = rsqrtf((float)(c + 1));
    if (i == N - 1) rowptr[N] = excl + c;   // == E
}

// CSR fill: 4 edges/thread -> 4 independent gather+atomic+store chains
__global__ void k_fill(const int* __restrict__ src, const int* __restrict__ dst,
                       const float* __restrict__ dinv, int* __restrict__ cursor,
                       uint32_t* __restrict__ epack) {
    int t = blockIdx.x * blockDim.x + threadIdx.x;
    if (t >= E / 4) return;
    const int4 s4 = reinterpret_cast<const int4*>(src)[t];
    const int4 d4 = reinterpret_cast<const int4*>(dst)[t];
    // 4 independent dinv gather pairs
    const float w0 = dinv[s4.x] * dinv[d4.x];
    const float w1 = dinv[s4.y] * dinv[d4.y];
    const float w2 = dinv[s4.z] * dinv[d4.z];
    const float w3 = dinv[s4.w] * dinv[d4.w];
    // 4 independent atomic slot-claims
    const int p0 = atomicAdd(&cursor[d4.x], 1);
    const int p1 = atomicAdd(&cursor[d4.y], 1);
    const int p2 = atomicAdd(&cursor[d4.z], 1);
    const int p3 = atomicAdd(&cursor[d4.w], 1);
    epack[p0] = (uint32_t)s4.x | ((uint32_t)__half_as_ushort(__float2half(w0)) << 16);
    epack[p1] = (uint32_t)s4.y | ((uint32_t)__half_as_ushort(__float2half(w1)) << 16);
    epack[p2] = (uint32_t)s4.z | ((uint32_t)__half_as_ushort(__float2half(w2)) << 16);
    epack[p3] = (uint32_t)s4.w | ((uint32_t)__half_as_ushort(__float2half(w3)) << 16);
}

// ---------------------------------------------------------------------------
// H[N,DOUT] = X[N,64] @ W[64,DOUT]; W staged in LDS. OutT = ushort(bf16)|float.
template <int DOUT, typename OutT>
__global__ void k_gemm(const float* __restrict__ X, const float* __restrict__ W,
                       OutT* __restrict__ H) {
    __shared__ float Ws[64 * DOUT];
    const int tid = threadIdx.x;
    for (int i = tid; i < 64 * DOUT; i += 256) Ws[i] = W[i];
    __syncthreads();

    constexpr int RPI = 256 / DOUT;
    const int col  = tid % DOUT;
    const int rsub = tid / DOUT;
    const int rowBase = blockIdx.x * 64;

    for (int r0 = 0; r0 < 64; r0 += RPI) {
        const int row = rowBase + r0 + rsub;
        if (row < N) {
            const float4* xr4 = reinterpret_cast<const float4*>(X + (size_t)row * 64);
            float acc = 0.0f;
#pragma unroll
            for (int k4 = 0; k4 < 16; ++k4) {
                float4 xv = xr4[k4];
                acc += xv.x * Ws[(4 * k4 + 0) * DOUT + col];
                acc += xv.y * Ws[(4 * k4 + 1) * DOUT + col];
                acc += xv.z * Ws[(4 * k4 + 2) * DOUT + col];
                acc += xv.w * Ws[(4 * k4 + 3) * DOUT + col];
            }
            if constexpr (sizeof(OutT) == 2)
                H[(size_t)row * DOUT + col] = f2bf(acc);
            else
                H[(size_t)row * DOUT + col] = acc;
        }
    }
}

// ---------------------------------------------------------------------------
// Layer-1 aggregation. One wave per node; 8 groups x 8 lanes.
__global__ void k_agg1(const int* __restrict__ rowptr, const uint32_t* __restrict__ epack,
                       const uint16_t* __restrict__ h1, const float* __restrict__ dinv,
                       const float* __restrict__ b1, float* __restrict__ y1) {
    const int gtid = blockIdx.x * blockDim.x + threadIdx.x;
    const int n    = gtid >> 6;
    const int lane = gtid & 63;
    if (n >= N) return;
    const int g  = lane >> 3;   // edge slot 0..7
    const int sl = lane & 7;    // 16B feature slice
    const int beg = rowptr[n], end = rowptr[n + 1];

    float acc[8] = {0.f, 0.f, 0.f, 0.f, 0.f, 0.f, 0.f, 0.f};
    for (int j = beg; j < end; j += 8) {
        const int jj = j + g;
        int s = 0; float wn = 0.0f;
        if (jj < end) {
            const uint32_t w = epack[jj];
            s  = (int)(w & 0xFFFFu);
            wn = __half2float(__ushort_as_half((uint16_t)(w >> 16)));
        }
        const uint4 v = *reinterpret_cast<const uint4*>(h1 + (size_t)s * DH + sl * 8);
        float f0, f1;
        bf2x(v.x, f0, f1); acc[0] += wn * f0; acc[1] += wn * f1;
        bf2x(v.y, f0, f1); acc[2] += wn * f0; acc[3] += wn * f1;
        bf2x(v.z, f0, f1); acc[4] += wn * f0; acc[5] += wn * f1;
        bf2x(v.w, f0, f1); acc[6] += wn * f0; acc[7] += wn * f1;
    }
#pragma unroll
    for (int m = 8; m < 64; m <<= 1)
#pragma unroll
        for (int k = 0; k < 8; ++k) acc[k] += __shfl_xor(acc[k], m);

    if (g < 2) {   // 16 lanes write 16B each = full 256B row
        const float di = dinv[n], d2 = di * di;
        const int fb = sl * 8 + g * 4;     // feature base of this lane's float4
        const uint2 sv = *reinterpret_cast<const uint2*>(h1 + (size_t)n * DH + fb);
        float s0, s1, s2, s3;
        bf2x(sv.x, s0, s1); bf2x(sv.y, s2, s3);
        const float4 bv = *reinterpret_cast<const float4*>(b1 + fb);
        float4 o;
        o.x = fmaxf(acc[g * 4 + 0] + s0 * d2 + bv.x, 0.f);
        o.y = fmaxf(acc[g * 4 + 1] + s1 * d2 + bv.y, 0.f);
        o.z = fmaxf(acc[g * 4 + 2] + s2 * d2 + bv.z, 0.f);
        o.w = fmaxf(acc[g * 4 + 3] + s3 * d2 + bv.w, 0.f);
        *reinterpret_cast<float4*>(y1 + (size_t)n * DH + fb) = o;
    }
}

// Layer-2 aggregation, same structure; row = 32 f32 = 8 lanes x float4.
__global__ void k_agg2(const int* __restrict__ rowptr, const uint32_t* __restrict__ epack,
                       const float* __restrict__ h2, const float* __restrict__ dinv,
                       const float* __restrict__ b2, float* __restrict__ out) {
    const int gtid = blockIdx.x * blockDim.x + threadIdx.x;
    const int n    = gtid >> 6;
    const int lane = gtid & 63;
    if (n >= N) return;
    const int g  = lane >> 3;
    const int sl = lane & 7;    // features [sl*4, sl*4+4)
    const int beg = rowptr[n], end = rowptr[n + 1];

    float acc[4] = {0.f, 0.f, 0.f, 0.f};
    for (int j = beg; j < end; j += 8) {
        const int jj = j + g;
        int s = 0; float wn = 0.0f;
        if (jj < end) {
            const uint32_t w = epack[jj];
            s  = (int)(w & 0xFFFFu);
            wn = __half2float(__ushort_as_half((uint16_t)(w >> 16)));
        }
        const float4 v = *reinterpret_cast<const float4*>(h2 + (size_t)s * DO + sl * 4);
        acc[0] += wn * v.x; acc[1] += wn * v.y;
        acc[2] += wn * v.z; acc[3] += wn * v.w;
    }
#pragma unroll
    for (int m = 8; m < 64; m <<= 1)
#pragma unroll
        for (int k = 0; k < 4; ++k) acc[k] += __shfl_xor(acc[k], m);

    if (g == 0) {  // 8 lanes x float4 = full 128B row
        const float di = dinv[n], d2 = di * di;
        const float4 sv = *reinterpret_cast<const float4*>(h2 + (size_t)n * DO + sl * 4);
        const float4 bv = *reinterpret_cast<const float4*>(b2 + sl * 4);
        float4 o;
        o.x = acc[0] + sv.x * d2 + bv.x;
        o.y = acc[1] + sv.y * d2 + bv.y;
        o.z = acc[2] + sv.z * d2 + bv.z;
        o.w = acc[3] + sv.w * d2 + bv.w;
        *reinterpret_cast<float4*>(out + (size_t)n * DO + sl * 4) = o;
    }
}

// 64B-align each ws sub-buffer (16B vector loads require it)
template <typename T>
T* alignp(char*& p, size_t count) {
    uintptr_t u = ((uintptr_t)p + 63) & ~(uintptr_t)63;
    p = (char*)(u + count * sizeof(T));
    return (T*)u;
}

}  // namespace

extern "C" void kernel_launch(void* const* d_in, const int* in_sizes, int n_in,
                              void* d_out, int out_size, void* d_ws, size_t ws_size,
                              hipStream_t stream) {
    const float* x   = (const float*)d_in[0];
    const int*   ei  = (const int*)d_in[1];   // [2,E] int32: row0=src, row1=dst
    const float* W1  = (const float*)d_in[2];
    const float* b1  = (const float*)d_in[3];
    const float* W2  = (const float*)d_in[4];
    const float* b2  = (const float*)d_in[5];
    float* out = (float*)d_out;

    const int* src = ei;
    const int* dst = ei + E;

    // workspace layout, each 64B-aligned; total ~23.6 MB
    char* p = (char*)d_ws;
    int*      cnt    = alignp<int>(p, N);
    int*      rowptr = alignp<int>(p, N + 1);
    int*      cursor = alignp<int>(p, N);
    float*    dinv   = alignp<float>(p, N);
    int*      incl   = alignp<int>(p, N);
    int*      bsum   = alignp<int>(p, NB);
    uint32_t* epack  = alignp<uint32_t>(p, E);
    uint16_t* h1     = alignp<uint16_t>(p, (size_t)N * DH);   // bf16
    float*    y1     = alignp<float>(p, (size_t)N * DH);
    float*    h2     = (float*)h1;    // aliases h1 (dead after agg1); 64B-aligned

    // 1. zero histogram
    hipLaunchKernelGGL(k_zero, dim3((N + 255) / 256), dim3(256), 0, stream, cnt);
    // 2. in-degree histogram (4 edges/thread)
    hipLaunchKernelGGL(k_count, dim3((E / 4 + 255) / 256), dim3(256), 0, stream, dst, cnt);
    // 3. device-wide scan -> rowptr/cursor, dinv
    hipLaunchKernelGGL(k_scanA, dim3(NB), dim3(256), 0, stream, cnt, incl, bsum);
    hipLaunchKernelGGL(k_scanB, dim3(1), dim3(256), 0, stream, bsum);
    hipLaunchKernelGGL(k_scanC, dim3(NB), dim3(256), 0, stream, cnt, incl, bsum,
                       rowptr, cursor, dinv);
    // 4. CSR fill (4 edges/thread)
    hipLaunchKernelGGL(k_fill, dim3((E / 4 + 255) / 256), dim3(256), 0, stream,
                       src, dst, dinv, cursor, epack);
    // 5. h1 = x @ W1  (bf16 out)
    hipLaunchKernelGGL((k_gemm<DH, uint16_t>), dim3((N + 63) / 64), dim3(256), 0, stream,
                       x, W1, h1);
    // 6. y1 = relu(aggregate(h1) + self + b1)
    hipLaunchKernelGGL(k_agg1, dim3((N * 64 + 255) / 256), dim3(256), 0, stream,
                       rowptr, epack, h1, dinv, b1, y1);
    // 7. h2 = y1 @ W2  (f32 out)
    hipLaunchKernelGGL((k_gemm<DO, float>), dim3((N + 63) / 64), dim3(256), 0, stream,
                       y1, W2, h2);
    // 8. out = aggregate(h2) + self + b2
    hipLaunchKernelGGL(k_agg2, dim3((N * 64 + 255) / 256), dim3(256), 0, stream,
                       rowptr, epack, h2, dinv, b2, out);
}

// Round 12
// 177.012 us; speedup vs baseline: 1.2132x; 1.2132x over previous
//
#include <hip/hip_runtime.h>
#include <hip/hip_fp16.h>
#include <cstddef>
#include <cstdint>

namespace {

constexpr int N  = 50000;   // nodes  (must fit u16 for edge packing)
constexpr int E  = 800000;  // edges
constexpr int DH = 64;      // hidden dim
constexpr int DO = 32;      // output dim
constexpr int NB = (N + 255) / 256;   // 196 scan blocks
static_assert(N < 65536, "src packed as u16");
static_assert(NB <= 256, "phase-B single tile");

__device__ inline float bf2f(uint16_t u) {
    union { uint32_t u; float f; } c; c.u = (uint32_t)u << 16; return c.f;
}
__device__ inline uint16_t f2bf(float f) {   // RTNE
    union { float f; uint32_t u; } c; c.f = f;
    uint32_t r = c.u + 0x7FFFu + ((c.u >> 16) & 1u);
    return (uint16_t)(r >> 16);
}
// unpack packed pair of bf16 (low = first in memory)
__device__ inline void bf2x(uint32_t p, float& a, float& b) {
    union { uint32_t u; float f; } c0, c1;
    c0.u = p << 16; c1.u = p & 0xFFFF0000u;
    a = c0.f; b = c1.f;
}

// ---------------------------------------------------------------------------
__global__ void k_zero(int* __restrict__ cnt) {
    int i = blockIdx.x * blockDim.x + threadIdx.x;
    if (i < N) cnt[i] = 0;
}

// in-degree histogram + CSR rank claim (1 edge/thread, high TLP).
// rank[e] = this edge's arrival index among edges sharing its dst.
__global__ void k_count(const int* __restrict__ dst, int* __restrict__ cnt,
                        int* __restrict__ rank) {
    int e = blockIdx.x * blockDim.x + threadIdx.x;
    if (e < E) rank[e] = atomicAdd(&cnt[dst[e]], 1);
}

// ---------------------------------------------------------------------------
// Device-wide exclusive scan of cnt, 3 phases.
__global__ void k_scanA(const int* __restrict__ cnt, int* __restrict__ incl,
                        int* __restrict__ bsum) {
    __shared__ int ts[256];
    const int t = threadIdx.x;
    const int i = blockIdx.x * 256 + t;
    const int v = (i < N) ? cnt[i] : 0;
    ts[t] = v;
    __syncthreads();
#pragma unroll
    for (int off = 1; off < 256; off <<= 1) {
        const int u = (t >= off) ? ts[t - off] : 0;
        __syncthreads();
        ts[t] += u;
        __syncthreads();
    }
    if (i < N) incl[i] = ts[t];
    if (t == 255) bsum[blockIdx.x] = ts[255];
}

__global__ void k_scanB(int* __restrict__ bsum) {
    __shared__ int ts[256];
    const int t = threadIdx.x;
    const int v = (t < NB) ? bsum[t] : 0;
    ts[t] = v;
    __syncthreads();
#pragma unroll
    for (int off = 1; off < 256; off <<= 1) {
        const int u = (t >= off) ? ts[t - off] : 0;
        __syncthreads();
        ts[t] += u;
        __syncthreads();
    }
    if (t < NB) bsum[t] = ts[t] - v;    // exclusive base for block t
}

__global__ void k_scanC(const int* __restrict__ cnt, const int* __restrict__ incl,
                        const int* __restrict__ bbase, int* __restrict__ rowptr,
                        float* __restrict__ dinv) {
    const int i = blockIdx.x * 256 + threadIdx.x;
    if (i >= N) return;
    const int c    = cnt[i];
    const int excl = bbase[blockIdx.x] + incl[i] - c;
    rowptr[i] = excl;
    dinv[i]   = rsqrtf((float)(c + 1));
    if (i == N - 1) rowptr[N] = excl + c;   // == E
}

// CSR fill, atomic-free: pos = rowptr[dst] + rank (unique by construction).
__global__ void k_fill(const int* __restrict__ src, const int* __restrict__ dst,
                       const int* __restrict__ rank, const int* __restrict__ rowptr,
                       const float* __restrict__ dinv, uint32_t* __restrict__ epack) {
    int e = blockIdx.x * blockDim.x + threadIdx.x;
    if (e >= E) return;
    const int s = src[e], d = dst[e];
    const int pos = rowptr[d] + rank[e];
    const float wn = dinv[s] * dinv[d];
    const uint16_t hb = __half_as_ushort(__float2half(wn));
    epack[pos] = (uint32_t)s | ((uint32_t)hb << 16);
}

// ---------------------------------------------------------------------------
// H[N,DOUT] = X[N,64] @ W[64,DOUT]; W staged in LDS. OutT = ushort(bf16)|float.
template <int DOUT, typename OutT>
__global__ void k_gemm(const float* __restrict__ X, const float* __restrict__ W,
                       OutT* __restrict__ H) {
    __shared__ float Ws[64 * DOUT];
    const int tid = threadIdx.x;
    for (int i = tid; i < 64 * DOUT; i += 256) Ws[i] = W[i];
    __syncthreads();

    constexpr int RPI = 256 / DOUT;
    const int col  = tid % DOUT;
    const int rsub = tid / DOUT;
    const int rowBase = blockIdx.x * 64;

    for (int r0 = 0; r0 < 64; r0 += RPI) {
        const int row = rowBase + r0 + rsub;
        if (row < N) {
            const float4* xr4 = reinterpret_cast<const float4*>(X + (size_t)row * 64);
            float acc = 0.0f;
#pragma unroll
            for (int k4 = 0; k4 < 16; ++k4) {
                float4 xv = xr4[k4];
                acc += xv.x * Ws[(4 * k4 + 0) * DOUT + col];
                acc += xv.y * Ws[(4 * k4 + 1) * DOUT + col];
                acc += xv.z * Ws[(4 * k4 + 2) * DOUT + col];
                acc += xv.w * Ws[(4 * k4 + 3) * DOUT + col];
            }
            if constexpr (sizeof(OutT) == 2)
                H[(size_t)row * DOUT + col] = f2bf(acc);
            else
                H[(size_t)row * DOUT + col] = acc;
        }
    }
}

// ---------------------------------------------------------------------------
// Layer-1 aggregation. One wave per node; 8 groups x 8 lanes.
__global__ void k_agg1(const int* __restrict__ rowptr, const uint32_t* __restrict__ epack,
                       const uint16_t* __restrict__ h1, const float* __restrict__ dinv,
                       const float* __restrict__ b1, float* __restrict__ y1) {
    const int gtid = blockIdx.x * blockDim.x + threadIdx.x;
    const int n    = gtid >> 6;
    const int lane = gtid & 63;
    if (n >= N) return;
    const int g  = lane >> 3;   // edge slot 0..7
    const int sl = lane & 7;    // 16B feature slice
    const int beg = rowptr[n], end = rowptr[n + 1];

    float acc[8] = {0.f, 0.f, 0.f, 0.f, 0.f, 0.f, 0.f, 0.f};
    for (int j = beg; j < end; j += 8) {
        const int jj = j + g;
        int s = 0; float wn = 0.0f;
        if (jj < end) {
            const uint32_t w = epack[jj];
            s  = (int)(w & 0xFFFFu);
            wn = __half2float(__ushort_as_half((uint16_t)(w >> 16)));
        }
        const uint4 v = *reinterpret_cast<const uint4*>(h1 + (size_t)s * DH + sl * 8);
        float f0, f1;
        bf2x(v.x, f0, f1); acc[0] += wn * f0; acc[1] += wn * f1;
        bf2x(v.y, f0, f1); acc[2] += wn * f0; acc[3] += wn * f1;
        bf2x(v.z, f0, f1); acc[4] += wn * f0; acc[5] += wn * f1;
        bf2x(v.w, f0, f1); acc[6] += wn * f0; acc[7] += wn * f1;
    }
#pragma unroll
    for (int m = 8; m < 64; m <<= 1)
#pragma unroll
        for (int k = 0; k < 8; ++k) acc[k] += __shfl_xor(acc[k], m);

    if (g < 2) {   // 16 lanes write 16B each = full 256B row
        const float di = dinv[n], d2 = di * di;
        const int fb = sl * 8 + g * 4;     // feature base of this lane's float4
        const uint2 sv = *reinterpret_cast<const uint2*>(h1 + (size_t)n * DH + fb);
        float s0, s1, s2, s3;
        bf2x(sv.x, s0, s1); bf2x(sv.y, s2, s3);
        const float4 bv = *reinterpret_cast<const float4*>(b1 + fb);
        float4 o;
        o.x = fmaxf(acc[g * 4 + 0] + s0 * d2 + bv.x, 0.f);
        o.y = fmaxf(acc[g * 4 + 1] + s1 * d2 + bv.y, 0.f);
        o.z = fmaxf(acc[g * 4 + 2] + s2 * d2 + bv.z, 0.f);
        o.w = fmaxf(acc[g * 4 + 3] + s3 * d2 + bv.w, 0.f);
        *reinterpret_cast<float4*>(y1 + (size_t)n * DH + fb) = o;
    }
}

// Layer-2 aggregation, same structure; row = 32 f32 = 8 lanes x float4.
__global__ void k_agg2(const int* __restrict__ rowptr, const uint32_t* __restrict__ epack,
                       const float* __restrict__ h2, const float* __restrict__ dinv,
                       const float* __restrict__ b2, float* __restrict__ out) {
    const int gtid = blockIdx.x * blockDim.x + threadIdx.x;
    const int n    = gtid >> 6;
    const int lane = gtid & 63;
    if (n >= N) return;
    const int g  = lane >> 3;
    const int sl = lane & 7;    // features [sl*4, sl*4+4)
    const int beg = rowptr[n], end = rowptr[n + 1];

    float acc[4] = {0.f, 0.f, 0.f, 0.f};
    for (int j = beg; j < end; j += 8) {
        const int jj = j + g;
        int s = 0; float wn = 0.0f;
        if (jj < end) {
            const uint32_t w = epack[jj];
            s  = (int)(w & 0xFFFFu);
            wn = __half2float(__ushort_as_half((uint16_t)(w >> 16)));
        }
        const float4 v = *reinterpret_cast<const float4*>(h2 + (size_t)s * DO + sl * 4);
        acc[0] += wn * v.x; acc[1] += wn * v.y;
        acc[2] += wn * v.z; acc[3] += wn * v.w;
    }
#pragma unroll
    for (int m = 8; m < 64; m <<= 1)
#pragma unroll
        for (int k = 0; k < 4; ++k) acc[k] += __shfl_xor(acc[k], m);

    if (g == 0) {  // 8 lanes x float4 = full 128B row
        const float di = dinv[n], d2 = di * di;
        const float4 sv = *reinterpret_cast<const float4*>(h2 + (size_t)n * DO + sl * 4);
        const float4 bv = *reinterpret_cast<const float4*>(b2 + sl * 4);
        float4 o;
        o.x = acc[0] + sv.x * d2 + bv.x;
        o.y = acc[1] + sv.y * d2 + bv.y;
        o.z = acc[2] + sv.z * d2 + bv.z;
        o.w = acc[3] + sv.w * d2 + bv.w;
        *reinterpret_cast<float4*>(out + (size_t)n * DO + sl * 4) = o;
    }
}

// 64B-align each ws sub-buffer (16B vector loads require it)
template <typename T>
T* alignp(char*& p, size_t count) {
    uintptr_t u = ((uintptr_t)p + 63) & ~(uintptr_t)63;
    p = (char*)(u + count * sizeof(T));
    return (T*)u;
}

}  // namespace

extern "C" void kernel_launch(void* const* d_in, const int* in_sizes, int n_in,
                              void* d_out, int out_size, void* d_ws, size_t ws_size,
                              hipStream_t stream) {
    const float* x   = (const float*)d_in[0];
    const int*   ei  = (const int*)d_in[1];   // [2,E] int32: row0=src, row1=dst
    const float* W1  = (const float*)d_in[2];
    const float* b1  = (const float*)d_in[3];
    const float* W2  = (const float*)d_in[4];
    const float* b2  = (const float*)d_in[5];
    float* out = (float*)d_out;

    const int* src = ei;
    const int* dst = ei + E;

    // workspace layout, each 64B-aligned; total ~26.8 MB (ws is ~256 MiB)
    char* p = (char*)d_ws;
    int*      cnt    = alignp<int>(p, N);
    int*      rowptr = alignp<int>(p, N + 1);
    int*      rank   = alignp<int>(p, E);
    float*    dinv   = alignp<float>(p, N);
    int*      incl   = alignp<int>(p, N);
    int*      bsum   = alignp<int>(p, NB);
    uint32_t* epack  = alignp<uint32_t>(p, E);
    uint16_t* h1     = alignp<uint16_t>(p, (size_t)N * DH);   // bf16
    float*    y1     = alignp<float>(p, (size_t)N * DH);
    float*    h2     = (float*)h1;    // aliases h1 (dead after agg1); 64B-aligned

    // 1. zero histogram
    hipLaunchKernelGGL(k_zero, dim3((N + 255) / 256), dim3(256), 0, stream, cnt);
    // 2. in-degree histogram + rank claim (1 edge/thread)
    hipLaunchKernelGGL(k_count, dim3((E + 255) / 256), dim3(256), 0, stream,
                       dst, cnt, rank);
    // 3. device-wide scan -> rowptr, dinv
    hipLaunchKernelGGL(k_scanA, dim3(NB), dim3(256), 0, stream, cnt, incl, bsum);
    hipLaunchKernelGGL(k_scanB, dim3(1), dim3(256), 0, stream, bsum);
    hipLaunchKernelGGL(k_scanC, dim3(NB), dim3(256), 0, stream, cnt, incl, bsum,
                       rowptr, dinv);
    // 4. CSR fill, atomic-free (pos = rowptr[dst] + rank)
    hipLaunchKernelGGL(k_fill, dim3((E + 255) / 256), dim3(256), 0, stream,
                       src, dst, rank, rowptr, dinv, epack);
    // 5. h1 = x @ W1  (bf16 out)
    hipLaunchKernelGGL((k_gemm<DH, uint16_t>), dim3((N + 63) / 64), dim3(256), 0, stream,
                       x, W1, h1);
    // 6. y1 = relu(aggregate(h1) + self + b1)
    hipLaunchKernelGGL(k_agg1, dim3((N * 64 + 255) / 256), dim3(256), 0, stream,
                       rowptr, epack, h1, dinv, b1, y1);
    // 7. h2 = y1 @ W2  (f32 out)
    hipLaunchKernelGGL((k_gemm<DO, float>), dim3((N + 63) / 64), dim3(256), 0, stream,
                       y1, W2, h2);
    // 8. out = aggregate(h2) + self + b2
    hipLaunchKernelGGL(k_agg2, dim3((N * 64 + 255) / 256), dim3(256), 0, stream,
                       rowptr, epack, h2, dinv, b2, out);
}

// Round 13
// 159.992 us; speedup vs baseline: 1.3423x; 1.1064x over previous
//
#include <hip/hip_runtime.h>
#include <hip/hip_fp16.h>
#include <cstddef>
#include <cstdint>

namespace {

constexpr int N  = 50000;   // nodes  (must fit u16 for edge packing)
constexpr int E  = 800000;  // edges
constexpr int DH = 64;      // hidden dim
constexpr int DO = 32;      // output dim
constexpr int NB = (N + 255) / 256;   // 196 scan blocks
static_assert(N < 65536, "src packed as u16");
static_assert(NB <= 256, "phase-B single tile");

__device__ inline float bf2f(uint16_t u) {
    union { uint32_t u; float f; } c; c.u = (uint32_t)u << 16; return c.f;
}
__device__ inline uint16_t f2bf(float f) {   // RTNE
    union { float f; uint32_t u; } c; c.f = f;
    uint32_t r = c.u + 0x7FFFu + ((c.u >> 16) & 1u);
    return (uint16_t)(r >> 16);
}
// unpack packed pair of bf16 (low = first in memory)
__device__ inline void bf2x(uint32_t p, float& a, float& b) {
    union { uint32_t u; float f; } c0, c1;
    c0.u = p << 16; c1.u = p & 0xFFFF0000u;
    a = c0.f; b = c1.f;
}

// ---------------------------------------------------------------------------
__global__ void k_zero(int* __restrict__ cnt) {
    int i = blockIdx.x * blockDim.x + threadIdx.x;
    if (i < N) cnt[i] = 0;
}

// in-degree histogram + CSR rank claim (1 edge/thread, high TLP).
__global__ void k_count(const int* __restrict__ dst, int* __restrict__ cnt,
                        int* __restrict__ rank) {
    int e = blockIdx.x * blockDim.x + threadIdx.x;
    if (e < E) rank[e] = atomicAdd(&cnt[dst[e]], 1);
}

// ---------------------------------------------------------------------------
// Device-wide exclusive scan of cnt, 3 phases.
__global__ void k_scanA(const int* __restrict__ cnt, int* __restrict__ incl,
                        int* __restrict__ bsum) {
    __shared__ int ts[256];
    const int t = threadIdx.x;
    const int i = blockIdx.x * 256 + t;
    const int v = (i < N) ? cnt[i] : 0;
    ts[t] = v;
    __syncthreads();
#pragma unroll
    for (int off = 1; off < 256; off <<= 1) {
        const int u = (t >= off) ? ts[t - off] : 0;
        __syncthreads();
        ts[t] += u;
        __syncthreads();
    }
    if (i < N) incl[i] = ts[t];
    if (t == 255) bsum[blockIdx.x] = ts[255];
}

__global__ void k_scanB(int* __restrict__ bsum) {
    __shared__ int ts[256];
    const int t = threadIdx.x;
    const int v = (t < NB) ? bsum[t] : 0;
    ts[t] = v;
    __syncthreads();
#pragma unroll
    for (int off = 1; off < 256; off <<= 1) {
        const int u = (t >= off) ? ts[t - off] : 0;
        __syncthreads();
        ts[t] += u;
        __syncthreads();
    }
    if (t < NB) bsum[t] = ts[t] - v;    // exclusive base for block t
}

__global__ void k_scanC(const int* __restrict__ cnt, const int* __restrict__ incl,
                        const int* __restrict__ bbase, int* __restrict__ rowptr,
                        float* __restrict__ dinv) {
    const int i = blockIdx.x * 256 + threadIdx.x;
    if (i >= N) return;
    const int c    = cnt[i];
    const int excl = bbase[blockIdx.x] + incl[i] - c;
    rowptr[i] = excl;
    dinv[i]   = rsqrtf((float)(c + 1));
    if (i == N - 1) rowptr[N] = excl + c;   // == E
}

// CSR fill, atomic-free: pos = rowptr[dst] + rank (unique by construction).
__global__ void k_fill(const int* __restrict__ src, const int* __restrict__ dst,
                       const int* __restrict__ rank, const int* __restrict__ rowptr,
                       const float* __restrict__ dinv, uint32_t* __restrict__ epack) {
    int e = blockIdx.x * blockDim.x + threadIdx.x;
    if (e >= E) return;
    const int s = src[e], d = dst[e];
    const int pos = rowptr[d] + rank[e];
    const float wn = dinv[s] * dinv[d];
    const uint16_t hb = __half_as_ushort(__float2half(wn));
    epack[pos] = (uint32_t)s | ((uint32_t)hb << 16);
}

// ---------------------------------------------------------------------------
// H[N,DOUT] = X[N,64] @ W[64,DOUT].  LDS-tiled: 64-row X tile + full W in LDS,
// X read from global exactly once (coalesced float4). Thread tile 4 x (DOUT/16).
// Per-output k-summation ascending -> bit-identical to previous version.
template <int DOUT, typename OutT>
__launch_bounds__(256)
__global__ void k_gemm(const float* __restrict__ X, const float* __restrict__ W,
                       OutT* __restrict__ H) {
    constexpr int CPT = DOUT / 16;          // cols per thread (4 or 2)
    static_assert(CPT == 4 || CPT == 2, "geometry");
    constexpr int XS = 68;                  // padded X row stride (dwords)
    __shared__ float Ws[64 * DOUT];
    __shared__ float Xs[64 * XS];

    const int tid = threadIdx.x;
    const int rowBase = blockIdx.x * 64;

    // stage W (row-major [64][DOUT]) as float4, coalesced
    constexpr int WF4 = 64 * DOUT / 4;
#pragma unroll
    for (int i = 0; i < WF4 / 256; ++i) {
        const int q = tid + i * 256;
        reinterpret_cast<float4*>(Ws)[q] = reinterpret_cast<const float4*>(W)[q];
    }
    // stage X tile (64 rows x 64 f32) as float4, coalesced; clamp tail rows
#pragma unroll
    for (int i = 0; i < 4; ++i) {
        const int q   = tid + i * 256;      // f4 index in [0,1024)
        const int row = q >> 4;             // 16 f4 per row
        const int kq  = q & 15;
        const int gr  = min(rowBase + row, N - 1);
        const float4 v = *reinterpret_cast<const float4*>(X + (size_t)gr * 64 + kq * 4);
        *reinterpret_cast<float4*>(&Xs[row * XS + kq * 4]) = v;
    }
    __syncthreads();

    const int rg = tid >> 4;                // row group 0..15  (4 rows each)
    const int cg = tid & 15;                // col group 0..15  (CPT cols each)

    float acc[4][CPT];
#pragma unroll
    for (int r = 0; r < 4; ++r)
#pragma unroll
        for (int c = 0; c < CPT; ++c) acc[r][c] = 0.0f;

#pragma unroll
    for (int k4 = 0; k4 < 16; ++k4) {
        const int k = k4 * 4;
        float xr[4][4];
#pragma unroll
        for (int r = 0; r < 4; ++r) {
            const float4 v = *reinterpret_cast<const float4*>(&Xs[(rg * 4 + r) * XS + k]);
            xr[r][0] = v.x; xr[r][1] = v.y; xr[r][2] = v.z; xr[r][3] = v.w;
        }
#pragma unroll
        for (int i = 0; i < 4; ++i) {
            float wv[CPT];
            if constexpr (CPT == 4) {
                const float4 v = *reinterpret_cast<const float4*>(&Ws[(k + i) * DOUT + cg * 4]);
                wv[0] = v.x; wv[1] = v.y; wv[2] = v.z; wv[3] = v.w;
            } else {
                const float2 v = *reinterpret_cast<const float2*>(&Ws[(k + i) * DOUT + cg * 2]);
                wv[0] = v.x; wv[1] = v.y;
            }
#pragma unroll
            for (int r = 0; r < 4; ++r)
#pragma unroll
                for (int c = 0; c < CPT; ++c) acc[r][c] += xr[r][i] * wv[c];
        }
    }

#pragma unroll
    for (int r = 0; r < 4; ++r) {
        const int row = rowBase + rg * 4 + r;
        if (row < N) {
            if constexpr (sizeof(OutT) == 2) {   // 4 bf16 packed as uint2
                uint2 o;
                o.x = (uint32_t)f2bf(acc[r][0]) | ((uint32_t)f2bf(acc[r][1]) << 16);
                o.y = (uint32_t)f2bf(acc[r][2]) | ((uint32_t)f2bf(acc[r][3]) << 16);
                *reinterpret_cast<uint2*>(&H[(size_t)row * DOUT + cg * 4]) = o;
            } else {                             // 2 f32 as float2
                float2 o; o.x = acc[r][0]; o.y = acc[r][1];
                *reinterpret_cast<float2*>(&H[(size_t)row * DOUT + cg * 2]) = o;
            }
        }
    }
}

// ---------------------------------------------------------------------------
// Layer-1 aggregation. One wave per node; 8 groups x 8 lanes.
__global__ void k_agg1(const int* __restrict__ rowptr, const uint32_t* __restrict__ epack,
                       const uint16_t* __restrict__ h1, const float* __restrict__ dinv,
                       const float* __restrict__ b1, float* __restrict__ y1) {
    const int gtid = blockIdx.x * blockDim.x + threadIdx.x;
    const int n    = gtid >> 6;
    const int lane = gtid & 63;
    if (n >= N) return;
    const int g  = lane >> 3;   // edge slot 0..7
    const int sl = lane & 7;    // 16B feature slice
    const int beg = rowptr[n], end = rowptr[n + 1];

    float acc[8] = {0.f, 0.f, 0.f, 0.f, 0.f, 0.f, 0.f, 0.f};
    for (int j = beg; j < end; j += 8) {
        const int jj = j + g;
        int s = 0; float wn = 0.0f;
        if (jj < end) {
            const uint32_t w = epack[jj];
            s  = (int)(w & 0xFFFFu);
            wn = __half2float(__ushort_as_half((uint16_t)(w >> 16)));
        }
        const uint4 v = *reinterpret_cast<const uint4*>(h1 + (size_t)s * DH + sl * 8);
        float f0, f1;
        bf2x(v.x, f0, f1); acc[0] += wn * f0; acc[1] += wn * f1;
        bf2x(v.y, f0, f1); acc[2] += wn * f0; acc[3] += wn * f1;
        bf2x(v.z, f0, f1); acc[4] += wn * f0; acc[5] += wn * f1;
        bf2x(v.w, f0, f1); acc[6] += wn * f0; acc[7] += wn * f1;
    }
#pragma unroll
    for (int m = 8; m < 64; m <<= 1)
#pragma unroll
        for (int k = 0; k < 8; ++k) acc[k] += __shfl_xor(acc[k], m);

    if (g < 2) {   // 16 lanes write 16B each = full 256B row
        const float di = dinv[n], d2 = di * di;
        const int fb = sl * 8 + g * 4;     // feature base of this lane's float4
        const uint2 sv = *reinterpret_cast<const uint2*>(h1 + (size_t)n * DH + fb);
        float s0, s1, s2, s3;
        bf2x(sv.x, s0, s1); bf2x(sv.y, s2, s3);
        const float4 bv = *reinterpret_cast<const float4*>(b1 + fb);
        float4 o;
        o.x = fmaxf(acc[g * 4 + 0] + s0 * d2 + bv.x, 0.f);
        o.y = fmaxf(acc[g * 4 + 1] + s1 * d2 + bv.y, 0.f);
        o.z = fmaxf(acc[g * 4 + 2] + s2 * d2 + bv.z, 0.f);
        o.w = fmaxf(acc[g * 4 + 3] + s3 * d2 + bv.w, 0.f);
        *reinterpret_cast<float4*>(y1 + (size_t)n * DH + fb) = o;
    }
}

// Layer-2 aggregation, same structure; row = 32 f32 = 8 lanes x float4.
__global__ void k_agg2(const int* __restrict__ rowptr, const uint32_t* __restrict__ epack,
                       const float* __restrict__ h2, const float* __restrict__ dinv,
                       const float* __restrict__ b2, float* __restrict__ out) {
    const int gtid = blockIdx.x * blockDim.x + threadIdx.x;
    const int n    = gtid >> 6;
    const int lane = gtid & 63;
    if (n >= N) return;
    const int g  = lane >> 3;
    const int sl = lane & 7;    // features [sl*4, sl*4+4)
    const int beg = rowptr[n], end = rowptr[n + 1];

    float acc[4] = {0.f, 0.f, 0.f, 0.f};
    for (int j = beg; j < end; j += 8) {
        const int jj = j + g;
        int s = 0; float wn = 0.0f;
        if (jj < end) {
            const uint32_t w = epack[jj];
            s  = (int)(w & 0xFFFFu);
            wn = __half2float(__ushort_as_half((uint16_t)(w >> 16)));
        }
        const float4 v = *reinterpret_cast<const float4*>(h2 + (size_t)s * DO + sl * 4);
        acc[0] += wn * v.x; acc[1] += wn * v.y;
        acc[2] += wn * v.z; acc[3] += wn * v.w;
    }
#pragma unroll
    for (int m = 8; m < 64; m <<= 1)
#pragma unroll
        for (int k = 0; k < 4; ++k) acc[k] += __shfl_xor(acc[k], m);

    if (g == 0) {  // 8 lanes x float4 = full 128B row
        const float di = dinv[n], d2 = di * di;
        const float4 sv = *reinterpret_cast<const float4*>(h2 + (size_t)n * DO + sl * 4);
        const float4 bv = *reinterpret_cast<const float4*>(b2 + sl * 4);
        float4 o;
        o.x = acc[0] + sv.x * d2 + bv.x;
        o.y = acc[1] + sv.y * d2 + bv.y;
        o.z = acc[2] + sv.z * d2 + bv.z;
        o.w = acc[3] + sv.w * d2 + bv.w;
        *reinterpret_cast<float4*>(out + (size_t)n * DO + sl * 4) = o;
    }
}

// 64B-align each ws sub-buffer (16B vector loads require it)
template <typename T>
T* alignp(char*& p, size_t count) {
    uintptr_t u = ((uintptr_t)p + 63) & ~(uintptr_t)63;
    p = (char*)(u + count * sizeof(T));
    return (T*)u;
}

}  // namespace

extern "C" void kernel_launch(void* const* d_in, const int* in_sizes, int n_in,
                              void* d_out, int out_size, void* d_ws, size_t ws_size,
                              hipStream_t stream) {
    const float* x   = (const float*)d_in[0];
    const int*   ei  = (const int*)d_in[1];   // [2,E] int32: row0=src, row1=dst
    const float* W1  = (const float*)d_in[2];
    const float* b1  = (const float*)d_in[3];
    const float* W2  = (const float*)d_in[4];
    const float* b2  = (const float*)d_in[5];
    float* out = (float*)d_out;

    const int* src = ei;
    const int* dst = ei + E;

    // workspace layout, each 64B-aligned; total ~26.8 MB (ws is ~256 MiB)
    char* p = (char*)d_ws;
    int*      cnt    = alignp<int>(p, N);
    int*      rowptr = alignp<int>(p, N + 1);
    int*      rank   = alignp<int>(p, E);
    float*    dinv   = alignp<float>(p, N);
    int*      incl   = alignp<int>(p, N);
    int*      bsum   = alignp<int>(p, NB);
    uint32_t* epack  = alignp<uint32_t>(p, E);
    uint16_t* h1     = alignp<uint16_t>(p, (size_t)N * DH);   // bf16
    float*    y1     = alignp<float>(p, (size_t)N * DH);
    float*    h2     = (float*)h1;    // aliases h1 (dead after agg1); 64B-aligned

    // 1. zero histogram
    hipLaunchKernelGGL(k_zero, dim3((N + 255) / 256), dim3(256), 0, stream, cnt);
    // 2. in-degree histogram + rank claim (1 edge/thread)
    hipLaunchKernelGGL(k_count, dim3((E + 255) / 256), dim3(256), 0, stream,
                       dst, cnt, rank);
    // 3. device-wide scan -> rowptr, dinv
    hipLaunchKernelGGL(k_scanA, dim3(NB), dim3(256), 0, stream, cnt, incl, bsum);
    hipLaunchKernelGGL(k_scanB, dim3(1), dim3(256), 0, stream, bsum);
    hipLaunchKernelGGL(k_scanC, dim3(NB), dim3(256), 0, stream, cnt, incl, bsum,
                       rowptr, dinv);
    // 4. CSR fill, atomic-free (pos = rowptr[dst] + rank)
    hipLaunchKernelGGL(k_fill, dim3((E + 255) / 256), dim3(256), 0, stream,
                       src, dst, rank, rowptr, dinv, epack);
    // 5. h1 = x @ W1  (bf16 out, LDS-tiled)
    hipLaunchKernelGGL((k_gemm<DH, uint16_t>), dim3((N + 63) / 64), dim3(256), 0, stream,
                       x, W1, h1);
    // 6. y1 = relu(aggregate(h1) + self + b1)
    hipLaunchKernelGGL(k_agg1, dim3((N * 64 + 255) / 256), dim3(256), 0, stream,
                       rowptr, epack, h1, dinv, b1, y1);
    // 7. h2 = y1 @ W2  (f32 out, LDS-tiled)
    hipLaunchKernelGGL((k_gemm<DO, float>), dim3((N + 63) / 64), dim3(256), 0, stream,
                       y1, W2, h2);
    // 8. out = aggregate(h2) + self + b2
    hipLaunchKernelGGL(k_agg2, dim3((N * 64 + 255) / 256), dim3(256), 0, stream,
                       rowptr, epack, h2, dinv, b2, out);
}

// Round 14
// 156.303 us; speedup vs baseline: 1.3740x; 1.0236x over previous
//
#include <hip/hip_runtime.h>
#include <hip/hip_fp16.h>
#include <cstddef>
#include <cstdint>

namespace {

constexpr int N  = 50000;   // nodes  (must fit u16 for edge packing)
constexpr int E  = 800000;  // edges
constexpr int DH = 64;      // hidden dim
constexpr int DO = 32;      // output dim
constexpr int NB = (N + 255) / 256;   // 196 scan blocks
constexpr int CB = (E + 255) / 256;   // 3125 count blocks (mega-kernel)
constexpr int GB = (N + 63) / 64;     // 782 gemm1 tiles   (mega-kernel)
constexpr int A1B = 3136;             // agg1 blocks: 12544 waves x 4 nodes
constexpr int NPW = 4;                // nodes per wave in agg1
static_assert(N < 65536, "src packed as u16");
static_assert(NB <= 256, "phase-B single tile");
static_assert((size_t)A1B * 4 * NPW >= N, "agg1 coverage");

__device__ inline uint16_t f2bf(float f) {   // RTNE
    union { float f; uint32_t u; } c; c.f = f;
    uint32_t r = c.u + 0x7FFFu + ((c.u >> 16) & 1u);
    return (uint16_t)(r >> 16);
}
// unpack packed pair of bf16 (low = first in memory)
__device__ inline void bf2x(uint32_t p, float& a, float& b) {
    union { uint32_t u; float f; } c0, c1;
    c0.u = p << 16; c1.u = p & 0xFFFF0000u;
    a = c0.f; b = c1.f;
}

// ---------------------------------------------------------------------------
__global__ void k_zero(int* __restrict__ cnt) {
    int i = blockIdx.x * blockDim.x + threadIdx.x;
    if (i < N) cnt[i] = 0;
}

// ---------------------------------------------------------------------------
// Mega-kernel: blocks [0,CB) = in-degree histogram + rank claim (latency-bound);
// blocks [CB, CB+GB) = gemm1 h1 = X @ W1 -> bf16 (compute-bound). Independent
// work, disjoint outputs -> co-residency overlaps the two regimes.
__launch_bounds__(256)
__global__ void k_pre(const int* __restrict__ dst, int* __restrict__ cnt,
                      int* __restrict__ rank, const float* __restrict__ X,
                      const float* __restrict__ W1, uint16_t* __restrict__ h1) {
    __shared__ float Ws[64 * DH];   // 16 KB
    __shared__ float Xs[64 * 68];   // 17.4 KB (padded stride 68)

    if (blockIdx.x < CB) {          // ---- histogram body
        const int e = blockIdx.x * 256 + threadIdx.x;
        if (e < E) rank[e] = atomicAdd(&cnt[dst[e]], 1);
        return;
    }

    // ---- gemm1 body (64-row tile, thread tile 4x4, ascending-k summation)
    const int tid = threadIdx.x;
    const int rowBase = (blockIdx.x - CB) * 64;

#pragma unroll
    for (int i = 0; i < 4; ++i) {   // stage W1: 64*64 f32 = 1024 f4
        const int q = tid + i * 256;
        reinterpret_cast<float4*>(Ws)[q] = reinterpret_cast<const float4*>(W1)[q];
    }
#pragma unroll
    for (int i = 0; i < 4; ++i) {   // stage X tile
        const int q   = tid + i * 256;
        const int row = q >> 4;
        const int kq  = q & 15;
        const int gr  = min(rowBase + row, N - 1);
        const float4 v = *reinterpret_cast<const float4*>(X + (size_t)gr * 64 + kq * 4);
        *reinterpret_cast<float4*>(&Xs[row * 68 + kq * 4]) = v;
    }
    __syncthreads();

    const int rg = tid >> 4;        // row group (4 rows)
    const int cg = tid & 15;        // col group (4 cols)
    float acc[4][4];
#pragma unroll
    for (int r = 0; r < 4; ++r)
#pragma unroll
        for (int c = 0; c < 4; ++c) acc[r][c] = 0.0f;

#pragma unroll
    for (int k4 = 0; k4 < 16; ++k4) {
        const int k = k4 * 4;
        float xr[4][4];
#pragma unroll
        for (int r = 0; r < 4; ++r) {
            const float4 v = *reinterpret_cast<const float4*>(&Xs[(rg * 4 + r) * 68 + k]);
            xr[r][0] = v.x; xr[r][1] = v.y; xr[r][2] = v.z; xr[r][3] = v.w;
        }
#pragma unroll
        for (int i = 0; i < 4; ++i) {
            const float4 v = *reinterpret_cast<const float4*>(&Ws[(k + i) * DH + cg * 4]);
            const float wv[4] = {v.x, v.y, v.z, v.w};
#pragma unroll
            for (int r = 0; r < 4; ++r)
#pragma unroll
                for (int c = 0; c < 4; ++c) acc[r][c] += xr[r][i] * wv[c];
        }
    }

#pragma unroll
    for (int r = 0; r < 4; ++r) {
        const int row = rowBase + rg * 4 + r;
        if (row < N) {
            uint2 o;
            o.x = (uint32_t)f2bf(acc[r][0]) | ((uint32_t)f2bf(acc[r][1]) << 16);
            o.y = (uint32_t)f2bf(acc[r][2]) | ((uint32_t)f2bf(acc[r][3]) << 16);
            *reinterpret_cast<uint2*>(&h1[(size_t)row * DH + cg * 4]) = o;
        }
    }
}

// ---------------------------------------------------------------------------
// Device-wide exclusive scan of cnt, 3 phases.
__global__ void k_scanA(const int* __restrict__ cnt, int* __restrict__ incl,
                        int* __restrict__ bsum) {
    __shared__ int ts[256];
    const int t = threadIdx.x;
    const int i = blockIdx.x * 256 + t;
    const int v = (i < N) ? cnt[i] : 0;
    ts[t] = v;
    __syncthreads();
#pragma unroll
    for (int off = 1; off < 256; off <<= 1) {
        const int u = (t >= off) ? ts[t - off] : 0;
        __syncthreads();
        ts[t] += u;
        __syncthreads();
    }
    if (i < N) incl[i] = ts[t];
    if (t == 255) bsum[blockIdx.x] = ts[255];
}

__global__ void k_scanB(int* __restrict__ bsum) {
    __shared__ int ts[256];
    const int t = threadIdx.x;
    const int v = (t < NB) ? bsum[t] : 0;
    ts[t] = v;
    __syncthreads();
#pragma unroll
    for (int off = 1; off < 256; off <<= 1) {
        const int u = (t >= off) ? ts[t - off] : 0;
        __syncthreads();
        ts[t] += u;
        __syncthreads();
    }
    if (t < NB) bsum[t] = ts[t] - v;    // exclusive base for block t
}

__global__ void k_scanC(const int* __restrict__ cnt, const int* __restrict__ incl,
                        const int* __restrict__ bbase, int* __restrict__ rowptr,
                        float* __restrict__ dinv) {
    const int i = blockIdx.x * 256 + threadIdx.x;
    if (i >= N) return;
    const int c    = cnt[i];
    const int excl = bbase[blockIdx.x] + incl[i] - c;
    rowptr[i] = excl;
    dinv[i]   = rsqrtf((float)(c + 1));
    if (i == N - 1) rowptr[N] = excl + c;   // == E
}

// CSR fill, atomic-free: pos = rowptr[dst] + rank (unique by construction).
__global__ void k_fill(const int* __restrict__ src, const int* __restrict__ dst,
                       const int* __restrict__ rank, const int* __restrict__ rowptr,
                       const float* __restrict__ dinv, uint32_t* __restrict__ epack) {
    int e = blockIdx.x * blockDim.x + threadIdx.x;
    if (e >= E) return;
    const int s = src[e], d = dst[e];
    const int pos = rowptr[d] + rank[e];
    const float wn = dinv[s] * dinv[d];
    const uint16_t hb = __half_as_ushort(__float2half(wn));
    epack[pos] = (uint32_t)s | ((uint32_t)hb << 16);
}

// ---------------------------------------------------------------------------
// Fused layer-1 aggregation + relu/bias + (y1 @ W2) -> h2 (bf16).
// One wave per NPW consecutive nodes; 8 groups(g) x 8 lanes(sl).
// Per-lane W2 slice w2r[k][c] = W2[sl*8+k][g*4+c] lives in registers, loaded
// once per wave. y1 never touches memory.
__launch_bounds__(256)
__global__ void k_agg1(const int* __restrict__ rowptr, const uint32_t* __restrict__ epack,
                       const uint16_t* __restrict__ h1, const float* __restrict__ dinv,
                       const float* __restrict__ W2, const float* __restrict__ b1,
                       uint16_t* __restrict__ h2) {
    const int wid  = (blockIdx.x * 256 + threadIdx.x) >> 6;
    const int lane = threadIdx.x & 63;
    const int g  = lane >> 3;   // edge slot / output col block
    const int sl = lane & 7;    // 16B feature slice (features sl*8 .. sl*8+7)

    float w2r[8][4];
#pragma unroll
    for (int k = 0; k < 8; ++k) {
        const float4 v = *reinterpret_cast<const float4*>(W2 + (size_t)(sl * 8 + k) * DO + g * 4);
        w2r[k][0] = v.x; w2r[k][1] = v.y; w2r[k][2] = v.z; w2r[k][3] = v.w;
    }
    float b1r[8];
    {
        const float4 a = *reinterpret_cast<const float4*>(b1 + sl * 8);
        const float4 b = *reinterpret_cast<const float4*>(b1 + sl * 8 + 4);
        b1r[0] = a.x; b1r[1] = a.y; b1r[2] = a.z; b1r[3] = a.w;
        b1r[4] = b.x; b1r[5] = b.y; b1r[6] = b.z; b1r[7] = b.w;
    }

    const int nBeg = wid * NPW;
    for (int ni = 0; ni < NPW; ++ni) {
        const int n = nBeg + ni;
        if (n >= N) return;                     // wave-uniform
        const int beg = rowptr[n], end = rowptr[n + 1];

        float acc[8] = {0.f, 0.f, 0.f, 0.f, 0.f, 0.f, 0.f, 0.f};
        for (int j = beg; j < end; j += 8) {
            const int jj = j + g;
            int s = 0; float wn = 0.0f;
            if (jj < end) {
                const uint32_t w = epack[jj];
                s  = (int)(w & 0xFFFFu);
                wn = __half2float(__ushort_as_half((uint16_t)(w >> 16)));
            }
            const uint4 v = *reinterpret_cast<const uint4*>(h1 + (size_t)s * DH + sl * 8);
            float f0, f1;
            bf2x(v.x, f0, f1); acc[0] += wn * f0; acc[1] += wn * f1;
            bf2x(v.y, f0, f1); acc[2] += wn * f0; acc[3] += wn * f1;
            bf2x(v.z, f0, f1); acc[4] += wn * f0; acc[5] += wn * f1;
            bf2x(v.w, f0, f1); acc[6] += wn * f0; acc[7] += wn * f1;
        }
#pragma unroll
        for (int m = 8; m < 64; m <<= 1)        // sum over the 8 edge-groups
#pragma unroll
            for (int k = 0; k < 8; ++k) acc[k] += __shfl_xor(acc[k], m);

        // y = relu(acc + self*d2 + b1)  (8 features of slice sl, in regs)
        const float di = dinv[n], d2 = di * di;
        const uint4 sv = *reinterpret_cast<const uint4*>(h1 + (size_t)n * DH + sl * 8);
        float y[8];
        {
            float f0, f1;
            bf2x(sv.x, f0, f1); y[0] = acc[0] + f0 * d2; y[1] = acc[1] + f1 * d2;
            bf2x(sv.y, f0, f1); y[2] = acc[2] + f0 * d2; y[3] = acc[3] + f1 * d2;
            bf2x(sv.z, f0, f1); y[4] = acc[4] + f0 * d2; y[5] = acc[5] + f1 * d2;
            bf2x(sv.w, f0, f1); y[6] = acc[6] + f0 * d2; y[7] = acc[7] + f1 * d2;
        }
#pragma unroll
        for (int k = 0; k < 8; ++k) y[k] = fmaxf(y[k] + b1r[k], 0.0f);

        // matvec partials for cols [g*4, g*4+4)
        float o[4] = {0.f, 0.f, 0.f, 0.f};
#pragma unroll
        for (int k = 0; k < 8; ++k)
#pragma unroll
            for (int c = 0; c < 4; ++c) o[c] += y[k] * w2r[k][c];
#pragma unroll
        for (int m = 1; m < 8; m <<= 1)         // sum over the 8 sl slices
#pragma unroll
            for (int c = 0; c < 4; ++c) o[c] += __shfl_xor(o[c], m);

        if (sl == 0) {                          // 8 lanes x 8B = full 64B h2 row
            uint2 pk;
            pk.x = (uint32_t)f2bf(o[0]) | ((uint32_t)f2bf(o[1]) << 16);
            pk.y = (uint32_t)f2bf(o[2]) | ((uint32_t)f2bf(o[3]) << 16);
            *reinterpret_cast<uint2*>(h2 + (size_t)n * DO + g * 4) = pk;
        }
    }
}

// ---------------------------------------------------------------------------
// Layer-2 aggregation from bf16 h2. One wave per node; 16 groups x 4 lanes
// (row = 32 bf16 = 64B = 4 x uint4) -> 16 rows in flight per load instr.
__global__ void k_agg2(const int* __restrict__ rowptr, const uint32_t* __restrict__ epack,
                       const uint16_t* __restrict__ h2, const float* __restrict__ dinv,
                       const float* __restrict__ b2, float* __restrict__ out) {
    const int gtid = blockIdx.x * blockDim.x + threadIdx.x;
    const int n    = gtid >> 6;
    const int lane = gtid & 63;
    if (n >= N) return;
    const int g  = lane >> 2;   // edge slot 0..15
    const int sl = lane & 3;    // features sl*8 .. sl*8+7
    const int beg = rowptr[n], end = rowptr[n + 1];

    float acc[8] = {0.f, 0.f, 0.f, 0.f, 0.f, 0.f, 0.f, 0.f};
    for (int j = beg; j < end; j += 16) {
        const int jj = j + g;
        int s = 0; float wn = 0.0f;
        if (jj < end) {
            const uint32_t w = epack[jj];
            s  = (int)(w & 0xFFFFu);
            wn = __half2float(__ushort_as_half((uint16_t)(w >> 16)));
        }
        const uint4 v = *reinterpret_cast<const uint4*>(h2 + (size_t)s * DO + sl * 8);
        float f0, f1;
        bf2x(v.x, f0, f1); acc[0] += wn * f0; acc[1] += wn * f1;
        bf2x(v.y, f0, f1); acc[2] += wn * f0; acc[3] += wn * f1;
        bf2x(v.z, f0, f1); acc[4] += wn * f0; acc[5] += wn * f1;
        bf2x(v.w, f0, f1); acc[6] += wn * f0; acc[7] += wn * f1;
    }
#pragma unroll
    for (int m = 4; m < 64; m <<= 1)    // sum over the 16 edge-groups
#pragma unroll
        for (int k = 0; k < 8; ++k) acc[k] += __shfl_xor(acc[k], m);

    if (g < 2) {   // 8 lanes x float4 = full 128B f32 out row
        const float di = dinv[n], d2 = di * di;
        const int fb = sl * 8 + g * 4;
        const uint2 sv = *reinterpret_cast<const uint2*>(h2 + (size_t)n * DO + fb);
        float s0, s1, s2, s3;
        bf2x(sv.x, s0, s1); bf2x(sv.y, s2, s3);
        const float4 bv = *reinterpret_cast<const float4*>(b2 + fb);
        float4 o;
        o.x = acc[g * 4 + 0] + s0 * d2 + bv.x;
        o.y = acc[g * 4 + 1] + s1 * d2 + bv.y;
        o.z = acc[g * 4 + 2] + s2 * d2 + bv.z;
        o.w = acc[g * 4 + 3] + s3 * d2 + bv.w;
        *reinterpret_cast<float4*>(out + (size_t)n * DO + fb) = o;
    }
}

// 64B-align each ws sub-buffer (16B vector loads require it)
template <typename T>
T* alignp(char*& p, size_t count) {
    uintptr_t u = ((uintptr_t)p + 63) & ~(uintptr_t)63;
    p = (char*)(u + count * sizeof(T));
    return (T*)u;
}

}  // namespace

extern "C" void kernel_launch(void* const* d_in, const int* in_sizes, int n_in,
                              void* d_out, int out_size, void* d_ws, size_t ws_size,
                              hipStream_t stream) {
    const float* x   = (const float*)d_in[0];
    const int*   ei  = (const int*)d_in[1];   // [2,E] int32: row0=src, row1=dst
    const float* W1  = (const float*)d_in[2];
    const float* b1  = (const float*)d_in[3];
    const float* W2  = (const float*)d_in[4];
    const float* b2  = (const float*)d_in[5];
    float* out = (float*)d_out;

    const int* src = ei;
    const int* dst = ei + E;

    // workspace layout, each 64B-aligned; total ~16.8 MB
    char* p = (char*)d_ws;
    int*      cnt    = alignp<int>(p, N);
    int*      rowptr = alignp<int>(p, N + 1);
    int*      rank   = alignp<int>(p, E);
    float*    dinv   = alignp<float>(p, N);
    int*      incl   = alignp<int>(p, N);
    int*      bsum   = alignp<int>(p, NB);
    uint32_t* epack  = alignp<uint32_t>(p, E);
    uint16_t* h1     = alignp<uint16_t>(p, (size_t)N * DH);   // bf16
    uint16_t* h2     = alignp<uint16_t>(p, (size_t)N * DO);   // bf16

    // 1. zero histogram
    hipLaunchKernelGGL(k_zero, dim3((N + 255) / 256), dim3(256), 0, stream, cnt);
    // 2. mega: histogram+rank (blocks [0,CB)) || gemm1 h1 = x@W1 (blocks [CB,CB+GB))
    hipLaunchKernelGGL(k_pre, dim3(CB + GB), dim3(256), 0, stream,
                       dst, cnt, rank, x, W1, h1);
    // 3. device-wide scan -> rowptr, dinv
    hipLaunchKernelGGL(k_scanA, dim3(NB), dim3(256), 0, stream, cnt, incl, bsum);
    hipLaunchKernelGGL(k_scanB, dim3(1), dim3(256), 0, stream, bsum);
    hipLaunchKernelGGL(k_scanC, dim3(NB), dim3(256), 0, stream, cnt, incl, bsum,
                       rowptr, dinv);
    // 4. CSR fill, atomic-free
    hipLaunchKernelGGL(k_fill, dim3((E + 255) / 256), dim3(256), 0, stream,
                       src, dst, rank, rowptr, dinv, epack);
    // 5. fused agg1 + relu/bias + @W2 -> h2 (bf16); y1 never hits memory
    hipLaunchKernelGGL(k_agg1, dim3(A1B), dim3(256), 0, stream,
                       rowptr, epack, h1, dinv, W2, b1, h2);
    // 6. out = aggregate(h2) + self + b2
    hipLaunchKernelGGL(k_agg2, dim3((N * 64 + 255) / 256), dim3(256), 0, stream,
                       rowptr, epack, h2, dinv, b2, out);
}